// Round 5
// baseline (231.342 us; speedup 1.0000x reference)
//
#include <hip/hip_runtime.h>

// Elementwise clamp: out = min(max(x, lo), hi)
// x: 33,554,432 fp32 (4194304 x 8). Pure streaming kernel:
// 128 MiB read + 128 MiB write = 268 MB -> ~42.7 us floor at 6.29 TB/s.
//
// R5 = R4 + NONTEMPORAL STORES (loads stay cached). Single-variable A/B.
// Evidence: R1 vs R2 (identical loop, nt-both vs cached) = -11 us for nt;
// R4 vs R2 (batched vs loop, both cached) = -7 us for batching.
// This round stacks them, keeping loads cached because FETCH_SIZE=64 MiB
// shows half the input is served from L3 (poison-fill leftovers) — nt loads
// would forfeit those hits. nt stores skip L2/L3 write-allocate on a
// one-touch 128 MiB output stream, preserving L3 for the read stream.
//
// Structure: per thread, 8 independent global_load_dwordx4 back-to-back
// (no store precedes any load -> no vmcnt store->load gating), one wait,
// clamp, 8 nontemporal stores. 4096 blocks x 256 x 8 float4 = exact.

typedef float f32x4 __attribute__((ext_vector_type(4)));

#define PT 8          // float4s per thread
#define BLOCK 256

__device__ __forceinline__ f32x4 clamp4(f32x4 v, float lo, float hi) {
    // fminf(fmaxf(..)) -> v_med3_f32 clamp idiom
    v.x = fminf(fmaxf(v.x, lo), hi);
    v.y = fminf(fmaxf(v.y, lo), hi);
    v.z = fminf(fmaxf(v.z, lo), hi);
    v.w = fminf(fmaxf(v.w, lo), hi);
    return v;
}

__global__ void __launch_bounds__(BLOCK) clamp_kernel(
    const f32x4* __restrict__ x,
    const float* __restrict__ cp,
    f32x4* __restrict__ out,
    int n4)
{
    const float lo = cp[0];
    const float hi = cp[1];
    const int base = blockIdx.x * (BLOCK * PT) + threadIdx.x;

    if (base + (PT - 1) * BLOCK < n4) {
        // Fast path: 8 cached loads in flight, zero stores before any load.
        f32x4 v[PT];
#pragma unroll
        for (int k = 0; k < PT; ++k)
            v[k] = x[base + k * BLOCK];
#pragma unroll
        for (int k = 0; k < PT; ++k) {
            f32x4 c = clamp4(v[k], lo, hi);
            __builtin_nontemporal_store(c, &out[base + k * BLOCK]);
        }
    } else {
        // Guarded tail (not taken at the exact 4194304x8 shape).
#pragma unroll
        for (int k = 0; k < PT; ++k) {
            int idx = base + k * BLOCK;
            if (idx < n4) {
                f32x4 c = clamp4(x[idx], lo, hi);
                __builtin_nontemporal_store(c, &out[idx]);
            }
        }
    }
}

extern "C" void kernel_launch(void* const* d_in, const int* in_sizes, int n_in,
                              void* d_out, int out_size, void* d_ws, size_t ws_size,
                              hipStream_t stream)
{
    const f32x4* x = (const f32x4*)d_in[0];
    const float* cp = (const float*)d_in[1];
    f32x4* out = (f32x4*)d_out;

    const int n = in_sizes[0];          // 33,554,432 fp32 elements
    const int n4 = n / 4;               // 8,388,608 float4s (exact)

    const int per_block = BLOCK * PT;   // 2048 float4s per block
    const int grid = (n4 + per_block - 1) / per_block;   // 4096 blocks

    clamp_kernel<<<grid, BLOCK, 0, stream>>>(x, cp, out, n4);
}